// Round 13
// baseline (260.797 us; speedup 1.0000x reference)
//
#include <hip/hip_runtime.h>
#include <math.h>

typedef __bf16 bf16;
typedef __bf16 bf16x8 __attribute__((ext_vector_type(8)));
typedef __bf16 bf16x4 __attribute__((ext_vector_type(4)));
typedef float f32x4 __attribute__((ext_vector_type(4)));
typedef float f32x16 __attribute__((ext_vector_type(16)));
typedef unsigned int u32;
typedef u32 u32x4 __attribute__((ext_vector_type(4)));

__device__ __forceinline__ void gload_lds16(const void* g, void* l) {
  __builtin_amdgcn_global_load_lds(
      (const __attribute__((address_space(1))) void*)g,
      (__attribute__((address_space(3))) void*)l, 16, 0, 0);
}

__device__ __forceinline__ u32 pack_bf16(float a, float b) {
  union { bf16 h; unsigned short s; } ua, ub;
  ua.h = (bf16)a; ub.h = (bf16)b;
  return (u32)ua.s | ((u32)ub.s << 16);
}

// ---------------- single fused cast kernel: all fp32 inputs -> bf16 -------
__global__ __launch_bounds__(256) void cast_all(const float* __restrict__ hs,
                                                const float* __restrict__ Wq,
                                                const float* __restrict__ Wk,
                                                const float* __restrict__ Wv,
                                                const float* __restrict__ Wo,
                                                bf16* __restrict__ hsb,
                                                bf16* __restrict__ Wqkv,
                                                bf16* __restrict__ Wob) {
  long i = (long)blockIdx.x * 256 + threadIdx.x;
  const float* s; bf16* d;
  if (i < 1048576)      { s = hs + i * 4;                 d = hsb  + i * 4; }
  else if (i < 2097152) { s = Wq + (i - 1048576) * 4;     d = Wqkv + (i - 1048576) * 4; }
  else if (i < 2359296) { s = Wk + (i - 2097152) * 4;     d = Wqkv + 4194304 + (i - 2097152) * 4; }
  else if (i < 2621440) { s = Wv + (i - 2359296) * 4;     d = Wqkv + 5242880 + (i - 2359296) * 4; }
  else                  { s = Wo + (i - 2621440) * 4;     d = Wob  + (i - 2621440) * 4; }
  float4 v = *(const float4*)s;
  bf16x4 o;
  o[0] = (bf16)v.x; o[1] = (bf16)v.y; o[2] = (bf16)v.z; o[3] = (bf16)v.w;
  *(bf16x4*)d = o;
}

// ---------------- QKV GEMM: 64x128 tile, dbuf, fused RoPE -----------------
// Q heads pre-scaled by (1/8)*log2(e) so attention can use exp2 directly.
__global__ __launch_bounds__(256) void gemm_qkv(const bf16* __restrict__ A,
                                                const bf16* __restrict__ B,
                                                const float* __restrict__ cosb,
                                                const float* __restrict__ sinb,
                                                bf16* __restrict__ QK,
                                                bf16* __restrict__ Vt_g,
                                                int K) {
  __shared__ bf16 As[2][64][64];
  __shared__ bf16 Bs[2][128][64];
  const int tid  = threadIdx.x;
  const int lane = tid & 63;
  const int w    = tid >> 6;
  const int m0 = blockIdx.y * 64;
  const int n0 = blockIdx.x * 128;
  const int wr = w >> 1, wc = w & 1;
  const int l15 = lane & 15, lq = lane >> 4;

  f32x4 acc[2][4] = {};

  const bf16* Ag = A + (long)(m0 + w * 16 + (lane >> 3)) * K + ((lane & 7) << 3);
  const bf16* Bg = B + (long)(n0 + w * 32 + (lane >> 3)) * K + ((lane & 7) << 3);

#pragma unroll
  for (int i = 0; i < 2; ++i)
    gload_lds16(Ag + (long)i * 8 * K, &As[0][w * 16 + i * 8][0]);
#pragma unroll
  for (int i = 0; i < 4; ++i)
    gload_lds16(Bg + (long)i * 8 * K, &Bs[0][w * 32 + i * 8][0]);
  __syncthreads();

  int cur = 0;
  for (int k0 = 0; k0 < K; k0 += 64) {
    if (k0 + 64 < K) {
#pragma unroll
      for (int i = 0; i < 2; ++i)
        gload_lds16(Ag + (long)i * 8 * K + k0 + 64, &As[cur ^ 1][w * 16 + i * 8][0]);
#pragma unroll
      for (int i = 0; i < 4; ++i)
        gload_lds16(Bg + (long)i * 8 * K + k0 + 64, &Bs[cur ^ 1][w * 32 + i * 8][0]);
    }
#pragma unroll
    for (int kk = 0; kk < 64; kk += 32) {
      bf16x8 a[2], b[4];
#pragma unroll
      for (int m = 0; m < 2; ++m)
        a[m] = *(const bf16x8*)&As[cur][wr * 32 + m * 16 + l15][kk + (lq << 3)];
#pragma unroll
      for (int n = 0; n < 4; ++n)
        b[n] = *(const bf16x8*)&Bs[cur][wc * 64 + n * 16 + l15][kk + (lq << 3)];
#pragma unroll
      for (int m = 0; m < 2; ++m)
#pragma unroll
        for (int n = 0; n < 4; ++n)
          acc[m][n] = __builtin_amdgcn_mfma_f32_16x16x32_bf16(a[m], b[n], acc[m][n], 0, 0, 0);
    }
    __syncthreads();
    cur ^= 1;
  }

  const int rb = m0 + wr * 32 + (lq << 2);
  if (n0 >= 2560) {
    const int cb = n0 + wc * 64 + l15;
#pragma unroll
    for (int m = 0; m < 2; ++m)
#pragma unroll
      for (int n = 0; n < 4; ++n)
#pragma unroll
        for (int j = 0; j < 4; ++j)
          Vt_g[(long)(cb + n * 16 - 2560) * 2048 + (rb + m * 16 + j)] = (bf16)acc[m][n][j];
  } else {
    const int colb = n0 + wc * 64;
    // Q heads: 1/8 (=1/sqrt(64)) * log2(e) so attn uses exp2; K heads: 1.0
    const float scale = (colb >> 6) < 32 ? 0.125f * 1.44269504f : 1.0f;
#pragma unroll
    for (int m = 0; m < 2; ++m)
#pragma unroll
      for (int j = 0; j < 4; ++j) {
        const int r = rb + m * 16 + j;
        const float* cp = cosb + (long)r * 64;
        const float* sp = sinb + (long)r * 64;
        bf16* qrow = QK + (long)r * 2560 + colb;
#pragma unroll
        for (int n = 0; n < 2; ++n) {
          const int d = n * 16 + l15;
          float c = cp[d], s = sp[d];
          float L = acc[m][n][j], H = acc[m][n + 2][j];
          qrow[d]      = (bf16)((L * c - H * s) * scale);
          qrow[d + 32] = (bf16)((H * c + L * s) * scale);
        }
      }
  }
}

// ---------------- O-proj GEMM: 64x128 tile, dbuf, fp32 out (unchanged) ----
__global__ __launch_bounds__(256) void gemm_bt_f32(const bf16* __restrict__ A,
                                                   const bf16* __restrict__ B,
                                                   float* __restrict__ C,
                                                   int K, int ldc) {
  __shared__ bf16 As[2][64][64];
  __shared__ bf16 Bs[2][128][64];
  const int tid  = threadIdx.x;
  const int lane = tid & 63;
  const int w    = tid >> 6;
  const int m0 = blockIdx.y * 64;
  const int n0 = blockIdx.x * 128;
  const int wr = w >> 1, wc = w & 1;
  const int l15 = lane & 15, lq = lane >> 4;

  f32x4 acc[2][4] = {};

  const bf16* Ag = A + (long)(m0 + w * 16 + (lane >> 3)) * K + ((lane & 7) << 3);
  const bf16* Bg = B + (long)(n0 + w * 32 + (lane >> 3)) * K + ((lane & 7) << 3);

#pragma unroll
  for (int i = 0; i < 2; ++i)
    gload_lds16(Ag + (long)i * 8 * K, &As[0][w * 16 + i * 8][0]);
#pragma unroll
  for (int i = 0; i < 4; ++i)
    gload_lds16(Bg + (long)i * 8 * K, &Bs[0][w * 32 + i * 8][0]);
  __syncthreads();

  int cur = 0;
  for (int k0 = 0; k0 < K; k0 += 64) {
    if (k0 + 64 < K) {
#pragma unroll
      for (int i = 0; i < 2; ++i)
        gload_lds16(Ag + (long)i * 8 * K + k0 + 64, &As[cur ^ 1][w * 16 + i * 8][0]);
#pragma unroll
      for (int i = 0; i < 4; ++i)
        gload_lds16(Bg + (long)i * 8 * K + k0 + 64, &Bs[cur ^ 1][w * 32 + i * 8][0]);
    }
#pragma unroll
    for (int kk = 0; kk < 64; kk += 32) {
      bf16x8 a[2], b[4];
#pragma unroll
      for (int m = 0; m < 2; ++m)
        a[m] = *(const bf16x8*)&As[cur][wr * 32 + m * 16 + l15][kk + (lq << 3)];
#pragma unroll
      for (int n = 0; n < 4; ++n)
        b[n] = *(const bf16x8*)&Bs[cur][wc * 64 + n * 16 + l15][kk + (lq << 3)];
#pragma unroll
      for (int m = 0; m < 2; ++m)
#pragma unroll
        for (int n = 0; n < 4; ++n)
          acc[m][n] = __builtin_amdgcn_mfma_f32_16x16x32_bf16(a[m], b[n], acc[m][n], 0, 0, 0);
    }
    __syncthreads();
    cur ^= 1;
  }

  const int rb = m0 + wr * 32 + (lq << 2);
  const int cb = n0 + wc * 64 + l15;
#pragma unroll
  for (int m = 0; m < 2; ++m)
#pragma unroll
    for (int n = 0; n < 4; ++n)
#pragma unroll
      for (int j = 0; j < 4; ++j)
        C[(long)(rb + m * 16 + j) * ldc + (cb + n * 16)] = acc[m][n][j];
}

// ---------------- attention v5: 32x32 swapped, in-register P, KV-split ----
// grid (2048/128, 32 heads, 2 kv-halves), 256 threads = 4 waves x 32 q-rows.
// Each block processes 16 KV tiles (half the sequence); writes UNNORMALIZED
// partial O (bf16) + partial row-sum (f32). attn_merge combines halves.
// Q pre-scaled by log2(e)/8 -> p = exp2(s).
__global__ __launch_bounds__(256) void attn_v5(const bf16* __restrict__ QK,
                                               const bf16* __restrict__ Vg,
                                               bf16* __restrict__ Opart,
                                               float* __restrict__ lsum) {
  constexpr int LDT = 72;
  __shared__ bf16 Kt[2][64][LDT];    // [buf][kv][d]
  __shared__ bf16 Vt[2][64][LDT];    // [buf][d][kv]
  const int h   = blockIdx.y;
  const int q0  = blockIdx.x * 128;
  const int bz  = blockIdx.z;
  const int kv0 = bz * 1024;
  const int kvh = h >> 2;
  const int tid = threadIdx.x, lane = tid & 63, w = tid >> 6;
  const int l31 = lane & 31, hi = lane >> 5;

  const bf16* qrow = QK + (long)(q0 + w * 32 + l31) * 2560 + h * 64;
  bf16x8 qf[4];
#pragma unroll
  for (int i = 0; i < 4; ++i)
    qf[i] = *(const bf16x8*)(qrow + i * 16 + hi * 8);

  const int sr = tid >> 3;          // 0..31
  const int sc = (tid & 7) << 3;    // 0..56
  const bf16* ksrc = QK + (long)(kv0 + sr) * 2560 + 2048 + kvh * 64 + sc;
  const bf16* vsrc = Vg + (long)(kvh * 64 + sr) * 2048 + kv0 + sc;

  f32x16 oacc[2] = {};
  float lrow = 0.f;

  bf16x8 kreg[2], vreg[2];
#pragma unroll
  for (int cc = 0; cc < 2; ++cc) {
    kreg[cc] = *(const bf16x8*)(ksrc + (long)cc * 32 * 2560);
    vreg[cc] = *(const bf16x8*)(vsrc + (long)cc * 32 * 2048);
  }

  for (int t = 0; t < 16; ++t) {
    const int b = t & 1;
#pragma unroll
    for (int cc = 0; cc < 2; ++cc) {
      *(bf16x8*)&Kt[b][sr + 32 * cc][sc] = kreg[cc];
      *(bf16x8*)&Vt[b][sr + 32 * cc][sc] = vreg[cc];
    }
    __syncthreads();
    if (t != 15) {
      ksrc += 64 * 2560;
      vsrc += 64;
#pragma unroll
      for (int cc = 0; cc < 2; ++cc) {
        kreg[cc] = *(const bf16x8*)(ksrc + (long)cc * 32 * 2560);
        vreg[cc] = *(const bf16x8*)(vsrc + (long)cc * 32 * 2048);
      }
    }

    // S^T[kv][q]: A=K rows, B=Q^T
    f32x16 sacc[2] = {};
#pragma unroll
    for (int kb = 0; kb < 2; ++kb)
#pragma unroll
      for (int i = 0; i < 4; ++i) {
        bf16x8 a = *(const bf16x8*)&Kt[b][kb * 32 + l31][i * 16 + hi * 8];
        sacc[kb] = __builtin_amdgcn_mfma_f32_32x32x16_bf16(a, qf[i], sacc[kb], 0, 0, 0);
      }

    // p = exp2(s) (Q carries log2e/8); pack to bf16 dwords
    u32 PK0[8], PK1[8];
#pragma unroll
    for (int u = 0; u < 8; ++u) {
      float p0 = exp2f(sacc[0][2 * u]);
      float p1 = exp2f(sacc[0][2 * u + 1]);
      lrow += p0 + p1;
      PK0[u] = pack_bf16(p0, p1);
    }
#pragma unroll
    for (int u = 0; u < 8; ++u) {
      float p0 = exp2f(sacc[1][2 * u]);
      float p1 = exp2f(sacc[1][2 * u + 1]);
      lrow += p0 + p1;
      PK1[u] = pack_bf16(p0, p1);
    }

    // PV: O^T[d][q] += V^T[d][kv] * P^T[kv][q]
#pragma unroll
    for (int kj = 0; kj < 4; ++kj) {
      const int c = kj & 1;
      u32 o0, o1, o2, o3;
      if (kj < 2) { o0 = PK0[4*c]; o1 = PK0[4*c+1]; o2 = PK0[4*c+2]; o3 = PK0[4*c+3]; }
      else        { o0 = PK1[4*c]; o1 = PK1[4*c+1]; o2 = PK1[4*c+2]; o3 = PK1[4*c+3]; }
      u32 s0 = hi ? o0 : o2;
      u32 s1 = hi ? o1 : o3;
      u32 X0 = (u32)__shfl_xor((int)s0, 32, 64);
      u32 X1 = (u32)__shfl_xor((int)s1, 32, 64);
      u32x4 bd;
      bd[0] = hi ? X0 : o0;
      bd[1] = hi ? X1 : o1;
      bd[2] = hi ? o2 : X0;
      bd[3] = hi ? o3 : X1;
      bf16x8 pb = __builtin_bit_cast(bf16x8, bd);
#pragma unroll
      for (int db = 0; db < 2; ++db) {
        bf16x8 av = *(const bf16x8*)&Vt[b][db * 32 + l31][kj * 16 + hi * 8];
        oacc[db] = __builtin_amdgcn_mfma_f32_32x32x16_bf16(av, pb, oacc[db], 0, 0, 0);
      }
    }
  }

  // partial row-sum and UNNORMALIZED partial O -> global (via LDS transpose)
  __syncthreads();
  float ltot = lrow + __shfl_xor(lrow, 32, 64);
  if (hi == 0)
    lsum[((long)bz * 32 + h) * 2048 + q0 + w * 32 + l31] = ltot;

  bf16* ob = (bf16*)&Kt[0][0][0] + w * 32 * 72;
#pragma unroll
  for (int db = 0; db < 2; ++db)
#pragma unroll
    for (int r = 0; r < 16; ++r) {
      int d = (r & 3) + 8 * (r >> 2) + 4 * hi + 32 * db;
      ob[(long)l31 * 72 + d] = (bf16)oacc[db][r];
    }
#pragma unroll
  for (int ps = 0; ps < 4; ++ps) {
    int r = ps * 8 + (lane >> 3);
    int cch = (lane & 7) << 3;
    bf16x8 v = *(const bf16x8*)&ob[r * 72 + cch];
    *(bf16x8*)(Opart + (((long)bz * 32 + h) * 2048 + q0 + w * 32 + r) * 64 + cch) = v;
  }
}

// ---------------- merge: AO[q][h*64+d] = (O0+O1)/(l0+l1) ------------------
__global__ __launch_bounds__(256) void attn_merge(const bf16* __restrict__ Opart,
                                                  const float* __restrict__ lsum,
                                                  bf16* __restrict__ AO) {
  long i = (long)blockIdx.x * 256 + threadIdx.x;   // 0 .. 32*2048*8-1
  int d8 = (int)(i & 7);
  int q  = (int)((i >> 3) & 2047);
  int h  = (int)(i >> 14);
  const bf16* p0 = Opart + ((long)h * 2048 + q) * 64 + d8 * 8;
  const bf16* p1 = Opart + ((long)(32 + h) * 2048 + q) * 64 + d8 * 8;
  float linv = 1.f / (lsum[h * 2048 + q] + lsum[(32 + h) * 2048 + q]);
  bf16x8 a = *(const bf16x8*)p0;
  bf16x8 b = *(const bf16x8*)p1;
  bf16x8 o;
#pragma unroll
  for (int k = 0; k < 8; ++k)
    o[k] = (bf16)(((float)a[k] + (float)b[k]) * linv);
  *(bf16x8*)(AO + (long)q * 2048 + h * 64 + d8 * 8) = o;
}

extern "C" void kernel_launch(void* const* d_in, const int* in_sizes, int n_in,
                              void* d_out, int out_size, void* d_ws, size_t ws_size,
                              hipStream_t stream) {
  const float* hs   = (const float*)d_in[0];
  const float* cosb = (const float*)d_in[1];
  const float* sinb = (const float*)d_in[2];
  const float* Wq   = (const float*)d_in[3];
  const float* Wk   = (const float*)d_in[4];
  const float* Wv   = (const float*)d_in[5];
  const float* Wo   = (const float*)d_in[6];
  float* out = (float*)d_out;

  char* ws = (char*)d_ws;
  bf16* hsb   = (bf16*)(ws);                    // [2048][2048]   8 MB
  bf16* Wqkv  = (bf16*)(ws + (8l  << 20));      // [3072][2048]  12 MB
  bf16* Wob   = (bf16*)(ws + (20l << 20));      // [2048][2048]   8 MB
  bf16* QKbuf = (bf16*)(ws + (28l << 20));      // [2048][2560]  10 MB
  bf16* Vt_g  = (bf16*)(ws + (38l << 20));      // [512][2048]    2 MB
  bf16* AO    = (bf16*)(ws + (40l << 20));      // [2048][2048]   8 MB
  bf16* Opart = (bf16*)(ws + (48l << 20));      // [2][32][2048][64] 16.8 MB
  float* lsum = (float*)(ws + (65l << 20));     // [2][32][2048]  0.5 MB

  cast_all<<<14336, 256, 0, stream>>>(hs, Wq, Wk, Wv, Wo, hsb, Wqkv, Wob);

  // QKV projection + fused RoPE (Q scaled by log2e/8)
  gemm_qkv<<<dim3(24, 32), 256, 0, stream>>>(hsb, Wqkv, cosb, sinb, QKbuf, Vt_g, 2048);

  // attention, KV-split x2 -> unnormalized partials
  attn_v5<<<dim3(16, 32, 2), 256, 0, stream>>>(QKbuf, Vt_g, Opart, lsum);

  // merge halves -> AO
  attn_merge<<<2048, 256, 0, stream>>>(Opart, lsum, AO);

  // output projection -> fp32
  gemm_bt_f32<<<dim3(16, 32), 256, 0, stream>>>(AO, Wob, out, 2048, 2048);
}